// Round 10
// baseline (180.991 us; speedup 1.0000x reference)
//
#include <hip/hip_runtime.h>
#include <hip/hip_bf16.h>

typedef __attribute__((ext_vector_type(4))) float f32x4;
typedef __attribute__((ext_vector_type(8))) __bf16 bf16x8;
typedef __attribute__((ext_vector_type(4))) unsigned short us4;
typedef __attribute__((ext_vector_type(8))) unsigned short us8;
typedef __attribute__((ext_vector_type(4))) unsigned int u32x4;

#define LDS_AS __attribute__((address_space(3)))
#define GLB_AS __attribute__((address_space(1)))

__device__ __forceinline__ float bf2f(unsigned short h) {
    return __builtin_bit_cast(float, (unsigned)h << 16);
}
__device__ __forceinline__ unsigned short f2bf(float f) {
    return __builtin_bit_cast(unsigned short, (__bf16)f);   // native RNE cvt
}
__device__ __forceinline__ us8 cvt8(f32x4 a, f32x4 b) {
    bf16x8 r;
    r[0] = (__bf16)a[0]; r[1] = (__bf16)a[1]; r[2] = (__bf16)a[2]; r[3] = (__bf16)a[3];
    r[4] = (__bf16)b[0]; r[5] = (__bf16)b[1]; r[6] = (__bf16)b[2]; r[7] = (__bf16)b[3];
    return __builtin_bit_cast(us8, r);
}
__device__ __forceinline__ void cp16(const void* g, void* l) {
    __builtin_amdgcn_global_load_lds((const GLB_AS unsigned int*)g,
                                     (LDS_AS unsigned int*)l, 16, 0, 0);
}

// ---------------------------------------------------------------- prep (+audio)
// Weights only now (frames/vecs cast fused into GEMM): wf/wv bf16, W1p pad,
// zero accumulators. ~17MB traffic.
#define NPREPB 544
#define NTOT 557056
__global__ __launch_bounds__(256) void prep_kernel(
    const float* __restrict__ Wfk, const float* __restrict__ Wfv,
    const float* __restrict__ Wvk, const float* __restrict__ Wvv,
    const float* __restrict__ Wout1, const float* __restrict__ audios, const float* __restrict__ Wav,
    unsigned short* __restrict__ wf, unsigned short* __restrict__ wv,
    float* __restrict__ W1p, float* __restrict__ hacc, float* __restrict__ qz,
    float* __restrict__ a_v, float* __restrict__ a_q_p)
{
    __shared__ float aud[128];
    const int t = threadIdx.x;
    if (blockIdx.x >= NPREPB) {              // audio: a_v = relu(audios @ Wav^T)
        const int b = blockIdx.x - NPREPB;
        if (t < 128) aud[t] = audios[b * 128 + t];
        __syncthreads();
        #pragma unroll
        for (int cc = 0; cc < 2; ++cc) {
            int c = 2 * t + cc;
            const float* wr = Wav + (size_t)c * 128;
            float s = 0.f;
            #pragma unroll
            for (int k4 = 0; k4 < 32; ++k4) {
                f32x4 wvv = *(const f32x4*)(wr + k4 * 4);
                s += wvv[0] * aud[k4 * 4] + wvv[1] * aud[k4 * 4 + 1]
                   + wvv[2] * aud[k4 * 4 + 2] + wvv[3] * aud[k4 * 4 + 3];
            }
            s = s > 0.f ? s : 0.f;
            a_v[b * 512 + c] = s;
            a_q_p[b * 512 + c] = s;
        }
        return;
    }
    for (int i = blockIdx.x * 256 + t; i < NTOT; i += NPREPB * 256) {
        int idx = i;
        if (idx < 77824) {                   // wf: 1024 x 76 us8 items (pad 600->608)
            int row = idx / 76, k = (idx - row * 76) * 8;
            const float* src = row < 512 ? Wfk + (size_t)row * 600 : Wfv + (size_t)(row - 512) * 600;
            us8 o = {0, 0, 0, 0, 0, 0, 0, 0};
            if (k < 600) o = cvt8(*(const f32x4*)(src + k), *(const f32x4*)(src + k + 4));
            *(us8*)(wf + (size_t)row * 608 + k) = o;
            continue;
        }
        idx -= 77824;
        if (idx < 98304) {                   // wv: 1024 x 96 us8 items
            int row = idx / 96, k = (idx - row * 96) * 8;
            const float* src = (row < 512 ? Wvk + (size_t)row * 768
                                          : Wvv + (size_t)(row - 512) * 768) + k;
            *(us8*)(wv + (size_t)row * 768 + k) = cvt8(*(const f32x4*)src, *(const f32x4*)(src + 4));
            continue;
        }
        idx -= 98304;
        if (idx < 344064) {                  // W1p: 768 x 448 f32x4 items (pad 1539->1792)
            int r = idx / 448, k = (idx - r * 448) * 4;
            f32x4 o;
            #pragma unroll
            for (int j = 0; j < 4; ++j) {
                int kk = k + j;
                o[j] = kk < 1539 ? Wout1[(size_t)r * 1539 + kk] : 0.f;
            }
            *(f32x4*)(W1p + (size_t)r * 1792 + k) = o;
            continue;
        }
        idx -= 344064;
        if (idx < 20480) {                   // zero h1acc+h2acc
            f32x4 z = {0, 0, 0, 0};
            *(f32x4*)(hacc + (size_t)idx * 4) = z;
            continue;
        }
        idx -= 20480;
        {                                    // zero f_q_p|v_q_p
            f32x4 z = {0, 0, 0, 0};
            *(f32x4*)(qz + (size_t)idx * 4) = z;
        }
    }
}

// ---------------------------------------------------------------- GEMM
// A: fp32 source, reg-staged (coalesced 128B-segment loads, 1-ahead) with
// in-register bf16 cvt + linear ds_write. B: bf16 weights via global_load_lds
// (2-ahead). 3-buffer rotation, ONE barrier/K-step, counted vmcnt. T1 swizzle.
// Issue order per iter: [A(kt+1) x4 loads, B(kt+2) x2 cp16]; vmcnt(2) after
// MFMA(kt) => B(kt+1) and A(kt+1) landed, B(kt+2) stays in flight.
// C[m][n] = relu(sum_k A[m][k]*B[n][k]) bf16; value-half col sums -> qout.
__global__ __launch_bounds__(256) void gemm_fused(
    const float* __restrict__ Aff, const unsigned short* __restrict__ Bf,
    unsigned short* __restrict__ Cfo, float* __restrict__ qf,
    const float* __restrict__ Afv, const unsigned short* __restrict__ Bv,
    unsigned short* __restrict__ Cvo, float* __restrict__ qv)
{
    __shared__ alignas(16) unsigned short sA[3][4096];
    __shared__ alignas(16) unsigned short sB[3][4096];
    const int t = threadIdx.x;
    const int w = t >> 6, l = t & 63;
    const float* A;
    const unsigned short* B;
    unsigned short* C;
    float* qout;
    int Kreal, Kp, ktiles, gshift, nwg, pb;
    if (blockIdx.x < 1024) { A = Aff; B = Bf; C = Cfo; qout = qf; Kreal = 600; Kp = 608; ktiles = 19; gshift = 8; nwg = 1024; pb = blockIdx.x; }
    else                   { A = Afv; B = Bv; C = Cvo; qout = qv; Kreal = 768; Kp = 768; ktiles = 24; gshift = 7; nwg = 512;  pb = blockIdx.x - 1024; }
    const int swz = (pb & 7) * (nwg >> 3) + (pb >> 3);
    const int bm = swz >> 3, bn = swz & 7;
    const int m0 = bm << 7, n0 = bn << 7;

    // B staging: 2 cp16/thread (row t>>2, chunk t&3)
    const int srow = t >> 2, sk0 = (t & 3) << 3;
    const unsigned short* gB = B + (size_t)(n0 + srow) * Kp + sk0;
    // A reg-staging: 4 rows/thread: w*32 + j*8 + (l>>3); col chunk (l&7)*4 floats.
    // Per load instr: 8 lanes cover one row's 32 cols = 128B contiguous.
    const int arow = w * 32 + (l >> 3);
    const int acol = (l & 7) * 4;
    const float* gA = A + (size_t)(m0 + arow) * Kreal + acol;
    const int wAidx = arow * 32 + acol;      // shorts: [row][32] row-major

    const int wr = w >> 1, wc = w & 1;
    const int fAoff = (wr * 64 + (l & 15)) * 32 + ((l >> 4) << 3);
    const int fBoff = (wc * 64 + (l & 15)) * 32 + ((l >> 4) << 3);

    f32x4 av[4];
    auto loadA = [&](int kt) {
        const bool ok = (kt * 32 + acol) < Kreal;
        const float* ga = gA + kt * 32;
        #pragma unroll
        for (int j = 0; j < 4; ++j)
            av[j] = ok ? *(const f32x4*)(ga + (size_t)j * 8 * Kreal)
                       : f32x4{0.f, 0.f, 0.f, 0.f};
    };
    auto writeA = [&](int buf) {
        unsigned short* wA = &sA[buf][0] + wAidx;
        #pragma unroll
        for (int j = 0; j < 4; ++j) {
            us4 o = {f2bf(av[j][0]), f2bf(av[j][1]), f2bf(av[j][2]), f2bf(av[j][3])};
            *(us4*)(wA + j * 256) = o;       // rows j*8 apart = 256 shorts
        }
    };
    auto stageB = [&](int buf, int kt) {
        char* lB = (char*)(&sB[buf][0]) + w * 1024;
        const unsigned short* gb = gB + kt * 32;
        cp16(gb, lB);
        cp16(gb + (size_t)64 * Kp, lB + 4096);
    };

    // prologue: A(0) to regs, B(0), B(1) in flight
    loadA(0);
    stageB(0, 0);
    stageB(1, 1);
    asm volatile("s_waitcnt vmcnt(4)" ::: "memory");    // A(0) landed
    writeA(0);
    asm volatile("s_waitcnt vmcnt(2)" ::: "memory");    // B(0) landed; B(1) in flight
    asm volatile("s_waitcnt lgkmcnt(0)" ::: "memory");
    __builtin_amdgcn_s_barrier();

    f32x4 acc[4][4] = {};
    int cur = 0;
    for (int kt = 0; kt < ktiles; ++kt) {
        int nxt = cur + 1; if (nxt == 3) nxt = 0;
        int nx2 = nxt + 1; if (nx2 == 3) nx2 = 0;
        if (kt + 1 < ktiles) loadA(kt + 1);             // 4 VM loads
        if (kt + 2 < ktiles) stageB(nx2, kt + 2);       // 2 VM cp16

        bf16x8 af[4], bfr[4];
        #pragma unroll
        for (int i = 0; i < 4; ++i) {
            af[i]  = *(const bf16x8*)(&sA[cur][0] + fAoff + i * 512);
            bfr[i] = *(const bf16x8*)(&sB[cur][0] + fBoff + i * 512);
        }
        #pragma unroll
        for (int mi = 0; mi < 4; ++mi)
            #pragma unroll
            for (int ni = 0; ni < 4; ++ni)
                acc[mi][ni] = __builtin_amdgcn_mfma_f32_16x16x32_bf16(af[mi], bfr[ni], acc[mi][ni], 0, 0, 0);

        if (kt + 1 < ktiles) {
            if (kt + 2 < ktiles) asm volatile("s_waitcnt vmcnt(2)" ::: "memory");
            else                 asm volatile("s_waitcnt vmcnt(0)" ::: "memory");
            __builtin_amdgcn_sched_barrier(0);
            writeA(nxt);                                 // A(kt+1) -> buf nxt
            asm volatile("s_waitcnt lgkmcnt(0)" ::: "memory");
            __builtin_amdgcn_sched_barrier(0);
            __builtin_amdgcn_s_barrier();
            __builtin_amdgcn_sched_barrier(0);
        }
        cur = nxt;
    }

    const int crow0 = m0 + wr * 64 + ((l >> 4) << 2);
    const int ccol0 = n0 + wc * 64 + (l & 15);
    #pragma unroll
    for (int mi = 0; mi < 4; ++mi)
        #pragma unroll
        for (int ni = 0; ni < 4; ++ni)
            #pragma unroll
            for (int j = 0; j < 4; ++j) {
                float v = acc[mi][ni][j];
                v = v > 0.f ? v : 0.f;
                C[(size_t)(crow0 + mi * 16 + j) * 1024 + (ccol0 + ni * 16)] = f2bf(v);
            }
    if (n0 >= 512) {                         // fused per-group value-half column sums
        const int g = m0 >> gshift;
        float csum[4];
        #pragma unroll
        for (int ni = 0; ni < 4; ++ni) {
            float s = 0.f;
            #pragma unroll
            for (int mi = 0; mi < 4; ++mi)
                #pragma unroll
                for (int j = 0; j < 4; ++j)
                    s += fmaxf(acc[mi][ni][j], 0.f);
            s += __shfl_xor(s, 16, 64);
            s += __shfl_xor(s, 32, 64);
            csum[ni] = s;
        }
        if (l < 16) {
            #pragma unroll
            for (int ni = 0; ni < 4; ++ni)
                atomicAdd(&qout[g * 512 + (ccol0 - 512) + ni * 16], csum[ni]);
        }
    }
}

// ---------------------------------------------------------------- scores
// q-vector in registers; 4 frames per wave, 1536 blocks. Blocks 0..63 zero fc|vc.
__global__ __launch_bounds__(256) void scores_kernel(
    const unsigned short* __restrict__ Cf, const unsigned short* __restrict__ Cv,
    const float* __restrict__ v_q_p, float* __restrict__ sbuf, float* __restrict__ fvz)
{
    const int t = threadIdx.x, bid = blockIdx.x;
    if (bid < 64) {
        f32x4 z = {0, 0, 0, 0};
        ((f32x4*)fvz)[bid * 256 + t] = z;
    }
    const int w = t >> 6, l = t & 63;
    int fbase, g, soff;
    const unsigned short* X;
    if (bid < 1024) { fbase = bid * 16 + w * 4; g = fbase >> 8; X = Cf; soff = 0; }
    else            { fbase = (bid - 1024) * 16 + w * 4; g = fbase >> 7; X = Cv; soff = 16384; }
    const float* vq = v_q_p + g * 512 + l * 8;
    f32x4 q0 = *(const f32x4*)vq;
    f32x4 q1 = *(const f32x4*)(vq + 4);
    #pragma unroll
    for (int i = 0; i < 4; ++i) {
        const int frame = fbase + i;
        u32x4 u = *(const u32x4*)(X + (size_t)frame * 1024 + l * 8);
        float acc = q0[0] * bf2f((unsigned short)(u[0] & 0xffff)) + q0[1] * bf2f((unsigned short)(u[0] >> 16))
                  + q0[2] * bf2f((unsigned short)(u[1] & 0xffff)) + q0[3] * bf2f((unsigned short)(u[1] >> 16))
                  + q1[0] * bf2f((unsigned short)(u[2] & 0xffff)) + q1[1] * bf2f((unsigned short)(u[2] >> 16))
                  + q1[2] * bf2f((unsigned short)(u[3] & 0xffff)) + q1[3] * bf2f((unsigned short)(u[3] >> 16));
        #pragma unroll
        for (int m = 1; m < 64; m <<= 1) acc += __shfl_xor(acc, m, 64);
        if (l == 0) sbuf[soff + frame] = acc * (1.f / 512.f);
    }
}

// ---------------------------------------------------------------- PV: softmax + weighted V sum
__global__ __launch_bounds__(256) void pv_kernel(
    const unsigned short* __restrict__ Cf, const unsigned short* __restrict__ Cv,
    const float* __restrict__ sbuf, float* __restrict__ fc, float* __restrict__ vc)
{
    __shared__ float ws[256];
    __shared__ float red[256];
    const int t = threadIdx.x, bid = blockIdx.x;
    int g, chunk, NF, soff;
    const unsigned short* X;
    float* outp;
    if (bid < 1024) { g = bid >> 4; chunk = bid & 15; NF = 256; X = Cf; soff = g * 256; outp = fc; }
    else { int b2 = bid - 1024; g = b2 >> 3; chunk = b2 & 7; NF = 128; X = Cv; soff = 16384 + g * 128; outp = vc; }
    float s = (t < NF) ? sbuf[soff + t] : -1e30f;
    red[t] = s;
    __syncthreads();
    for (int st = 128; st > 0; st >>= 1) { if (t < st) red[t] = fmaxf(red[t], red[t + st]); __syncthreads(); }
    float m = red[0];
    __syncthreads();
    float e = (t < NF) ? __expf(s - m) : 0.f;
    ws[t] = e;
    red[t] = e;
    __syncthreads();
    for (int st = 128; st > 0; st >>= 1) { if (t < st) red[t] += red[t + st]; __syncthreads(); }
    float inv = 1.f / red[0];
    const int f0 = g * NF + chunk * 16;
    const unsigned int* q = (const unsigned int*)X + (size_t)f0 * 512 + 256 + t;
    float s0 = 0.f, s1 = 0.f;
    #pragma unroll 4
    for (int f = 0; f < 16; ++f) {
        float a = ws[chunk * 16 + f];
        unsigned u = q[(size_t)f * 512];
        s0 += a * bf2f((unsigned short)(u & 0xffff));
        s1 += a * bf2f((unsigned short)(u >> 16));
    }
    atomicAdd(&outp[g * 512 + 2 * t],     s0 * inv);
    atomicAdd(&outp[g * 512 + 2 * t + 1], s1 * inv);
}

// ---------------------------------------------------------------- batched GEMV body
__device__ __forceinline__ void gemv_body(
    const float* __restrict__ X, int ldx, int dorelu,
    const float* __restrict__ W, int ldw, float* __restrict__ Y, int ldy,
    int nc, int kc, int bc)
{
    __shared__ float xs[4096];
    const int t = threadIdx.x;
    #pragma unroll
    for (int j = 0; j < 16; ++j) {
        int idx = t + j * 256;
        float v = X[(size_t)(bc * 32 + (idx >> 7)) * ldx + kc * 128 + (idx & 127)];
        xs[idx] = dorelu ? (v > 0.f ? v : 0.f) : v;
    }
    __syncthreads();
    const int r = t & 63, bg = t >> 6;
    const int row = nc * 64 + r;
    const float* wrow = W + (size_t)row * ldw + kc * 128;
    float acc[8] = {};
    #pragma unroll 8
    for (int k4 = 0; k4 < 32; ++k4) {
        f32x4 wvv = *(const f32x4*)(wrow + k4 * 4);
        #pragma unroll
        for (int bb = 0; bb < 8; ++bb) {
            f32x4 xv = *(const f32x4*)(xs + (bg * 8 + bb) * 128 + k4 * 4);
            acc[bb] += wvv[0] * xv[0] + wvv[1] * xv[1] + wvv[2] * xv[2] + wvv[3] * xv[3];
        }
    }
    #pragma unroll
    for (int bb = 0; bb < 8; ++bb)
        atomicAdd(&Y[(size_t)(bc * 32 + bg * 8 + bb) * ldy + row], acc[bb]);
}

// update: 3 ops x 8 nc x 4 kc x 2 bc = 192 blocks
__global__ __launch_bounds__(256) void update_kernel(
    const float* __restrict__ Wff_f, const float* __restrict__ Wff_v, const float* __restrict__ Wff_a,
    int iter, const float* __restrict__ fc, const float* __restrict__ vc, const float* __restrict__ a_v,
    float* __restrict__ f_q_p, float* __restrict__ v_q_p, float* __restrict__ a_q_p)
{
    int id = blockIdx.x;
    const int op = id >> 6; id &= 63;
    const int nc = id & 7, kc = (id >> 3) & 3, bc = id >> 5;
    const float* W = (op == 0 ? Wff_f : op == 1 ? Wff_v : Wff_a) + (size_t)iter * 262144;
    const float* X = op == 0 ? fc : op == 1 ? vc : a_v;
    float* Y = op == 0 ? f_q_p : op == 1 ? v_q_p : a_q_p;
    gemv_body(X, 512, 0, W, 512, Y, 512, nc, kc, bc);
}

// generic: grid = NC*KC*2
__global__ __launch_bounds__(256) void gemvb_kernel(
    const float* __restrict__ X, int ldx, int dorelu,
    const float* __restrict__ W, int ldw, float* __restrict__ Y, int ldy,
    int NC, int KC)
{
    int bid = blockIdx.x;
    const int nc = bid % NC; bid /= NC;
    const int kc = bid % KC;
    const int bc = bid / KC;
    gemv_body(X, ldx, dorelu, W, ldw, Y, ldy, nc, kc, bc);
}

// ---------------------------------------------------------------- normalize + build feats
__global__ __launch_bounds__(512) void normfeats_kernel(
    const float* __restrict__ a_q_p, const float* __restrict__ f_q_p, const float* __restrict__ v_q_p,
    const float* __restrict__ metas, float* __restrict__ feats)
{
    __shared__ float red[512];
    const int t = threadIdx.x, b = blockIdx.x;
    float a = a_q_p[b * 512 + t];
    red[t] = a;
    __syncthreads();
    for (int s = 256; s > 0; s >>= 1) { if (t < s) red[t] += red[t + s]; __syncthreads(); }
    float mean = red[0] * (1.f / 512.f);
    __syncthreads();
    float d = a - mean;
    red[t] = d * d;
    __syncthreads();
    for (int s = 256; s > 0; s >>= 1) { if (t < s) red[t] += red[t + s]; __syncthreads(); }
    float sd = sqrtf(red[0] * (1.f / 511.f));
    float* fr = feats + (size_t)b * 1792;
    fr[t]        = f_q_p[b * 512 + t];
    fr[512 + t]  = v_q_p[b * 512 + t];
    fr[1024 + t] = d / sd;
    if (t < 256) {
        float v = 0.f;
        if (t == 0) v = metas[b * 5 + 1] * (1.f / 1500.f);
        else if (t == 1) v = metas[b * 5 + 4] * 0.2f;
        else if (t == 2) {
            float du = metas[b * 5 + 3] - metas[b * 5 + 2];
            v = (du > 8000.f ? 100.f : du) * 0.01f;
        }
        fr[1536 + t] = v;
    }
}

// ---------------------------------------------------------------- MLP layers 3+4
__global__ __launch_bounds__(256) void mlp34_kernel(
    const float* __restrict__ h2acc, const float* __restrict__ W3, const float* __restrict__ W4,
    float* __restrict__ out)
{
    __shared__ float xs[512];
    __shared__ float part[256];
    __shared__ float h3[64];
    const int t = threadIdx.x, b = blockIdx.x;
    {
        float v0 = h2acc[(size_t)b * 512 + t];
        float v1 = h2acc[(size_t)b * 512 + 256 + t];
        xs[t] = v0 > 0.f ? v0 : 0.f;
        xs[256 + t] = v1 > 0.f ? v1 : 0.f;
    }
    __syncthreads();
    const int r = t & 63, q = t >> 6;
    const float* wrow = W3 + (size_t)r * 512 + q * 128;
    float acc = 0.f;
    #pragma unroll 8
    for (int k4 = 0; k4 < 32; ++k4) {
        f32x4 wvv = *(const f32x4*)(wrow + k4 * 4);
        f32x4 xv  = *(const f32x4*)(xs + q * 128 + k4 * 4);
        acc += wvv[0] * xv[0] + wvv[1] * xv[1] + wvv[2] * xv[2] + wvv[3] * xv[3];
    }
    part[t] = acc;
    __syncthreads();
    if (t < 64) {
        float h = part[t] + part[t + 64] + part[t + 128] + part[t + 192];
        h3[t] = h > 0.f ? h : 0.f;
    }
    __syncthreads();
    if (t < 64) {
        float v = h3[t] * W4[t];
        #pragma unroll
        for (int m = 1; m < 64; m <<= 1) v += __shfl_xor(v, m, 64);
        if (t == 0) out[b] = 1.f / (1.f + __expf(-v));
    }
}

// ---------------------------------------------------------------- launch
extern "C" void kernel_launch(void* const* d_in, const int* in_sizes, int n_in,
                              void* d_out, int out_size, void* d_ws, size_t ws_size,
                              hipStream_t stream)
{
    const float* metas  = (const float*)d_in[0];
    const float* frames = (const float*)d_in[2];
    const float* vecs   = (const float*)d_in[4];
    const float* audios = (const float*)d_in[6];
    const float* Wfk   = (const float*)d_in[8];
    const float* Wfv   = (const float*)d_in[9];
    const float* Wvk   = (const float*)d_in[10];
    const float* Wvv   = (const float*)d_in[11];
    const float* Wav   = (const float*)d_in[12];
    const float* Wff_f = (const float*)d_in[13];
    const float* Wff_v = (const float*)d_in[14];
    const float* Wff_a = (const float*)d_in[15];
    const float* Wout1 = (const float*)d_in[16];
    const float* Wout2 = (const float*)d_in[17];
    const float* Wout3 = (const float*)d_in[18];
    const float* Wout4 = (const float*)d_in[19];
    float* out = (float*)d_out;

    char* p = (char*)d_ws;
    auto alloc = [&](size_t n) { char* r = p; p += (n + 255) & ~(size_t)255; return r; };
    unsigned short* wf  = (unsigned short*)alloc(1024ull * 608 * 2);
    unsigned short* wv  = (unsigned short*)alloc(1024ull * 768 * 2);
    unsigned short* Cf  = (unsigned short*)alloc(16384ull * 1024 * 2);
    unsigned short* Cv  = (unsigned short*)alloc(8192ull * 1024 * 2);
    float* W1p   = (float*)alloc(768ull * 1792 * 4);
    float* feats = (float*)alloc(64ull * 1792 * 4);
    float* qbuf  = (float*)alloc(2ull * 64 * 512 * 4);     // f_q_p | v_q_p (zeroed in prep)
    float* f_q_p = qbuf;
    float* v_q_p = qbuf + 64 * 512;
    float* a_q_p = (float*)alloc(64ull * 512 * 4);
    float* a_v   = (float*)alloc(64ull * 512 * 4);
    float* fvc   = (float*)alloc(2ull * 64 * 512 * 4);     // fc | vc (zeroed in scores)
    float* fcb   = fvc;
    float* vcb   = fvc + 64 * 512;
    float* hacc  = (float*)alloc(81920ull * 4);            // h1acc (64*768) | h2acc (64*512)
    float* h1acc = hacc;
    float* h2acc = hacc + 64 * 768;
    float* sbuf  = (float*)alloc(24576ull * 4);            // f scores | v scores

    prep_kernel<<<NPREPB + 64, 256, 0, stream>>>(Wfk, Wfv, Wvk, Wvv, Wout1, audios, Wav,
                                                 wf, wv, W1p, hacc, qbuf, a_v, a_q_p);
    gemm_fused<<<1536, 256, 0, stream>>>(frames, wf, Cf, f_q_p, vecs, wv, Cv, v_q_p);
    for (int i = 0; i < 2; ++i) {
        scores_kernel<<<1536, 256, 0, stream>>>(Cf, Cv, v_q_p, sbuf, fvc);
        pv_kernel<<<1536, 256, 0, stream>>>(Cf, Cv, sbuf, fcb, vcb);
        update_kernel<<<192, 256, 0, stream>>>(Wff_f, Wff_v, Wff_a, i, fcb, vcb, a_v,
                                               f_q_p, v_q_p, a_q_p);
    }
    normfeats_kernel<<<64, 512, 0, stream>>>(a_q_p, f_q_p, v_q_p, metas, feats);
    gemvb_kernel<<<336, 256, 0, stream>>>(feats, 1792, 0, W1p, 1792, h1acc, 768, 12, 14);
    gemvb_kernel<<<96, 256, 0, stream>>>(h1acc, 768, 1, Wout2, 768, h2acc, 512, 8, 6);
    mlp34_kernel<<<64, 256, 0, stream>>>(h2acc, Wout3, Wout4, out);
}

// Round 11
// 175.157 us; speedup vs baseline: 1.0333x; 1.0333x over previous
//
#include <hip/hip_runtime.h>
#include <hip/hip_bf16.h>

typedef __attribute__((ext_vector_type(4))) float f32x4;
typedef __attribute__((ext_vector_type(8))) __bf16 bf16x8;
typedef __attribute__((ext_vector_type(8))) unsigned short us8;
typedef __attribute__((ext_vector_type(4))) unsigned int u32x4;

#define LDS_AS __attribute__((address_space(3)))
#define GLB_AS __attribute__((address_space(1)))

__device__ __forceinline__ float bf2f(unsigned short h) {
    return __builtin_bit_cast(float, (unsigned)h << 16);
}
__device__ __forceinline__ unsigned short f2bf(float f) {
    return __builtin_bit_cast(unsigned short, (__bf16)f);   // native RNE cvt
}
__device__ __forceinline__ us8 cvt8(f32x4 a, f32x4 b) {
    bf16x8 r;
    r[0] = (__bf16)a[0]; r[1] = (__bf16)a[1]; r[2] = (__bf16)a[2]; r[3] = (__bf16)a[3];
    r[4] = (__bf16)b[0]; r[5] = (__bf16)b[1]; r[6] = (__bf16)b[2]; r[7] = (__bf16)b[3];
    return __builtin_bit_cast(us8, r);
}
__device__ __forceinline__ void cp16(const void* g, void* l) {
    __builtin_amdgcn_global_load_lds((const GLB_AS unsigned int*)g,
                                     (LDS_AS unsigned int*)l, 16, 0, 0);
}

// ---------------------------------------------------------------- prep (+audio)
// Block-uniform segment dispatch; each segment = exactly 4 strided items/thread
// (no tails, no per-item branch chains). ~115MB, BW-shaped.
// segments: frames 1216 | wf 76 | vecs 768 | wv 96 | W1p 336 | zeros 36 | audio 64
__global__ __launch_bounds__(256) void prep_kernel(
    const float* __restrict__ frames, const float* __restrict__ Wfk, const float* __restrict__ Wfv,
    const float* __restrict__ vecs, const float* __restrict__ Wvk, const float* __restrict__ Wvv,
    const float* __restrict__ Wout1, const float* __restrict__ audios, const float* __restrict__ Wav,
    unsigned short* __restrict__ fbf, unsigned short* __restrict__ wf,
    unsigned short* __restrict__ vbf, unsigned short* __restrict__ wv,
    float* __restrict__ W1p, float* __restrict__ zbase,
    float* __restrict__ a_v, float* __restrict__ a_q_p)
{
    const int t = threadIdx.x;
    int bid = blockIdx.x;
    if (bid < 1216) {                        // frames: 16384 x 76 us8 chunks
        #pragma unroll
        for (int j = 0; j < 4; ++j) {
            int i = bid * 256 + t + j * (1216 * 256);
            int row = i / 76, k = (i - row * 76) * 8;
            us8 o = {0, 0, 0, 0, 0, 0, 0, 0};
            if (k < 600) {
                const float* s = frames + (size_t)row * 600 + k;
                o = cvt8(*(const f32x4*)s, *(const f32x4*)(s + 4));
            }
            *(us8*)(fbf + (size_t)row * 608 + k) = o;
        }
        return;
    }
    bid -= 1216;
    if (bid < 76) {                          // wf: 1024 x 76 (rows 0-511 Wfk, rest Wfv)
        #pragma unroll
        for (int j = 0; j < 4; ++j) {
            int i = bid * 256 + t + j * (76 * 256);
            int row = i / 76, k = (i - row * 76) * 8;
            const float* src = row < 512 ? Wfk + (size_t)row * 600 : Wfv + (size_t)(row - 512) * 600;
            us8 o = {0, 0, 0, 0, 0, 0, 0, 0};
            if (k < 600) o = cvt8(*(const f32x4*)(src + k), *(const f32x4*)(src + k + 4));
            *(us8*)(wf + (size_t)row * 608 + k) = o;
        }
        return;
    }
    bid -= 76;
    if (bid < 768) {                         // vecs: 8192 x 96
        #pragma unroll
        for (int j = 0; j < 4; ++j) {
            int i = bid * 256 + t + j * (768 * 256);
            int row = i / 96, k = (i - row * 96) * 8;
            const float* s = vecs + (size_t)row * 768 + k;
            *(us8*)(vbf + (size_t)row * 768 + k) = cvt8(*(const f32x4*)s, *(const f32x4*)(s + 4));
        }
        return;
    }
    bid -= 768;
    if (bid < 96) {                          // wv: 1024 x 96
        #pragma unroll
        for (int j = 0; j < 4; ++j) {
            int i = bid * 256 + t + j * (96 * 256);
            int row = i / 96, k = (i - row * 96) * 8;
            const float* src = (row < 512 ? Wvk + (size_t)row * 768
                                          : Wvv + (size_t)(row - 512) * 768) + k;
            *(us8*)(wv + (size_t)row * 768 + k) = cvt8(*(const f32x4*)src, *(const f32x4*)(src + 4));
        }
        return;
    }
    bid -= 96;
    if (bid < 336) {                         // W1p: 768 x 448 f32x4 (pad 1539->1792)
        #pragma unroll
        for (int j = 0; j < 4; ++j) {
            int i = bid * 256 + t + j * (336 * 256);
            int r = i / 448, k = (i - r * 448) * 4;
            f32x4 o;
            #pragma unroll
            for (int q = 0; q < 4; ++q) {
                int kk = k + q;
                o[q] = kk < 1539 ? Wout1[(size_t)r * 1539 + kk] : 0.f;
            }
            *(f32x4*)(W1p + (size_t)r * 1792 + k) = o;
        }
        return;
    }
    bid -= 336;
    if (bid < 36) {                          // zero hacc|qbuf (147456 floats = 36864 f32x4)
        f32x4 z = {0, 0, 0, 0};
        #pragma unroll
        for (int j = 0; j < 4; ++j) {
            int i = bid * 256 + t + j * (36 * 256);
            *(f32x4*)(zbase + (size_t)i * 4) = z;
        }
        return;
    }
    bid -= 36;
    {                                        // audio: a_v = relu(audios @ Wav^T)
        __shared__ float aud[128];
        const int b = bid;
        if (t < 128) aud[t] = audios[b * 128 + t];
        __syncthreads();
        #pragma unroll
        for (int cc = 0; cc < 2; ++cc) {
            int c = 2 * t + cc;
            const float* wr = Wav + (size_t)c * 128;
            float s = 0.f;
            #pragma unroll
            for (int k4 = 0; k4 < 32; ++k4) {
                f32x4 wvv = *(const f32x4*)(wr + k4 * 4);
                s += wvv[0] * aud[k4 * 4] + wvv[1] * aud[k4 * 4 + 1]
                   + wvv[2] * aud[k4 * 4 + 2] + wvv[3] * aud[k4 * 4 + 3];
            }
            s = s > 0.f ? s : 0.f;
            a_v[b * 512 + c] = s;
            a_q_p[b * 512 + c] = s;
        }
    }
}

// ---------------------------------------------------------------- GEMM (bf16 in, m97 tile,
// 3-buffer rotation, 2-ahead prefetch, ONE barrier/K-step, counted vmcnt(4),
// T1 XCD swizzle, T2-lite LDS chunk swizzle, both ops in one dispatch).
// LDS slot (row r, 16B-chunk c) holds global chunk c^(r&3): achieved by
// XOR-ing the per-lane SOURCE address (dest stays linear, m104/m173);
// fragment reads XOR the chunk index back => 8-way bank conflict -> 4-way.
// C[m][n] = relu(sum_k A[m][k]*B[n][k]) bf16; value-half col sums -> qout.
__global__ __launch_bounds__(256) void gemm_bt_relu(
    const unsigned short* __restrict__ Af, const unsigned short* __restrict__ Bf,
    unsigned short* __restrict__ Cfo, float* __restrict__ qf,
    const unsigned short* __restrict__ Av, const unsigned short* __restrict__ Bv,
    unsigned short* __restrict__ Cvo, float* __restrict__ qv)
{
    __shared__ alignas(16) unsigned short sA[3][4096];
    __shared__ alignas(16) unsigned short sB[3][4096];
    const int t = threadIdx.x;
    const int w = t >> 6, l = t & 63;
    const unsigned short *A, *B;
    unsigned short* C;
    float* qout;
    int Kp, ktiles, gshift, nwg, pb;
    if (blockIdx.x < 1024) { A = Af; B = Bf; C = Cfo; qout = qf; Kp = 608; ktiles = 19; gshift = 8; nwg = 1024; pb = blockIdx.x; }
    else                   { A = Av; B = Bv; C = Cvo; qout = qv; Kp = 768; ktiles = 24; gshift = 7; nwg = 512;  pb = blockIdx.x - 1024; }
    const int swz = (pb & 7) * (nwg >> 3) + (pb >> 3);
    const int bm = swz >> 3, bn = swz & 7;
    const int m0 = bm << 7, n0 = bn << 7;

    // staging: row t>>2; source chunk = (t&3) XOR (row&3)  [dest chunk = t&3]
    const int srow = t >> 2;
    const int schunk = (t & 3) ^ ((t >> 2) & 3);
    const unsigned short* gA = A + (size_t)(m0 + srow) * Kp + (schunk << 3);
    const unsigned short* gB = B + (size_t)(n0 + srow) * Kp + (schunk << 3);

    const int wr = w >> 1, wc = w & 1;
    // fragment read: logical chunk l>>4 lives at slot (l>>4) ^ (row&3), row&3 == l&3
    const int rsw = (((l >> 4) ^ (l & 3)) << 3);
    const int fAoff = (wr * 64 + (l & 15)) * 32 + rsw;
    const int fBoff = (wc * 64 + (l & 15)) * 32 + rsw;

    auto stage = [&](int buf, int kt) {
        char* lA = (char*)(&sA[buf][0]) + w * 1024;
        char* lB = (char*)(&sB[buf][0]) + w * 1024;
        const unsigned short* ga = gA + kt * 32;
        const unsigned short* gb = gB + kt * 32;
        cp16(ga, lA);
        cp16(ga + (size_t)64 * Kp, lA + 4096);   // row+64: (row&3) unchanged
        cp16(gb, lB);
        cp16(gb + (size_t)64 * Kp, lB + 4096);
    };

    stage(0, 0);                             // prologue: 2 tiles in flight
    stage(1, 1);
    f32x4 acc[4][4] = {};
    int cur = 0;
    for (int kt = 0; kt < ktiles; ++kt) {
        if (kt + 1 < ktiles) {
            asm volatile("s_waitcnt vmcnt(4)" ::: "memory");   // tile kt landed; kt+1 in flight
        } else {
            asm volatile("s_waitcnt vmcnt(0)" ::: "memory");
        }
        __builtin_amdgcn_sched_barrier(0);
        __builtin_amdgcn_s_barrier();
        __builtin_amdgcn_sched_barrier(0);

        bf16x8 af[4], bfr[4];
        #pragma unroll
        for (int i = 0; i < 4; ++i) {
            af[i]  = *(const bf16x8*)(&sA[cur][0] + fAoff + i * 512);
            bfr[i] = *(const bf16x8*)(&sB[cur][0] + fBoff + i * 512);
        }
        #pragma unroll
        for (int mi = 0; mi < 4; ++mi)
            #pragma unroll
            for (int ni = 0; ni < 4; ++ni)
                acc[mi][ni] = __builtin_amdgcn_mfma_f32_16x16x32_bf16(af[mi], bfr[ni], acc[mi][ni], 0, 0, 0);

        if (kt + 2 < ktiles) {
            int b2 = cur + 2; if (b2 >= 3) b2 -= 3;
            stage(b2, kt + 2);               // lands ~2 compute phases from now
        }
        cur = (cur + 1 == 3) ? 0 : cur + 1;
    }

    const int crow0 = m0 + wr * 64 + ((l >> 4) << 2);
    const int ccol0 = n0 + wc * 64 + (l & 15);
    #pragma unroll
    for (int mi = 0; mi < 4; ++mi)
        #pragma unroll
        for (int ni = 0; ni < 4; ++ni)
            #pragma unroll
            for (int j = 0; j < 4; ++j) {
                float v = acc[mi][ni][j];
                v = v > 0.f ? v : 0.f;
                C[(size_t)(crow0 + mi * 16 + j) * 1024 + (ccol0 + ni * 16)] = f2bf(v);
            }
    if (n0 >= 512) {                         // fused per-group value-half column sums
        const int g = m0 >> gshift;
        float csum[4];
        #pragma unroll
        for (int ni = 0; ni < 4; ++ni) {
            float s = 0.f;
            #pragma unroll
            for (int mi = 0; mi < 4; ++mi)
                #pragma unroll
                for (int j = 0; j < 4; ++j)
                    s += fmaxf(acc[mi][ni][j], 0.f);
            s += __shfl_xor(s, 16, 64);
            s += __shfl_xor(s, 32, 64);
            csum[ni] = s;
        }
        if (l < 16) {
            #pragma unroll
            for (int ni = 0; ni < 4; ++ni)
                atomicAdd(&qout[g * 512 + (ccol0 - 512) + ni * 16], csum[ni]);
        }
    }
}

// ---------------------------------------------------------------- scores
// q-vector in registers; 4 frames per wave, 1536 blocks. Blocks 0..63 zero fc|vc.
__global__ __launch_bounds__(256) void scores_kernel(
    const unsigned short* __restrict__ Cf, const unsigned short* __restrict__ Cv,
    const float* __restrict__ v_q_p, float* __restrict__ sbuf, float* __restrict__ fvz)
{
    const int t = threadIdx.x, bid = blockIdx.x;
    if (bid < 64) {
        f32x4 z = {0, 0, 0, 0};
        ((f32x4*)fvz)[bid * 256 + t] = z;
    }
    const int w = t >> 6, l = t & 63;
    int fbase, g, soff;
    const unsigned short* X;
    if (bid < 1024) { fbase = bid * 16 + w * 4; g = fbase >> 8; X = Cf; soff = 0; }
    else            { fbase = (bid - 1024) * 16 + w * 4; g = fbase >> 7; X = Cv; soff = 16384; }
    const float* vq = v_q_p + g * 512 + l * 8;
    f32x4 q0 = *(const f32x4*)vq;
    f32x4 q1 = *(const f32x4*)(vq + 4);
    #pragma unroll
    for (int i = 0; i < 4; ++i) {
        const int frame = fbase + i;
        u32x4 u = *(const u32x4*)(X + (size_t)frame * 1024 + l * 8);
        float acc = q0[0] * bf2f((unsigned short)(u[0] & 0xffff)) + q0[1] * bf2f((unsigned short)(u[0] >> 16))
                  + q0[2] * bf2f((unsigned short)(u[1] & 0xffff)) + q0[3] * bf2f((unsigned short)(u[1] >> 16))
                  + q1[0] * bf2f((unsigned short)(u[2] & 0xffff)) + q1[1] * bf2f((unsigned short)(u[2] >> 16))
                  + q1[2] * bf2f((unsigned short)(u[3] & 0xffff)) + q1[3] * bf2f((unsigned short)(u[3] >> 16));
        #pragma unroll
        for (int m = 1; m < 64; m <<= 1) acc += __shfl_xor(acc, m, 64);
        if (l == 0) sbuf[soff + frame] = acc * (1.f / 512.f);
    }
}

// ---------------------------------------------------------------- PV: softmax + weighted V sum
__global__ __launch_bounds__(256) void pv_kernel(
    const unsigned short* __restrict__ Cf, const unsigned short* __restrict__ Cv,
    const float* __restrict__ sbuf, float* __restrict__ fc, float* __restrict__ vc)
{
    __shared__ float ws[256];
    __shared__ float red[256];
    const int t = threadIdx.x, bid = blockIdx.x;
    int g, chunk, NF, soff;
    const unsigned short* X;
    float* outp;
    if (bid < 1024) { g = bid >> 4; chunk = bid & 15; NF = 256; X = Cf; soff = g * 256; outp = fc; }
    else { int b2 = bid - 1024; g = b2 >> 3; chunk = b2 & 7; NF = 128; X = Cv; soff = 16384 + g * 128; outp = vc; }
    float s = (t < NF) ? sbuf[soff + t] : -1e30f;
    red[t] = s;
    __syncthreads();
    for (int st = 128; st > 0; st >>= 1) { if (t < st) red[t] = fmaxf(red[t], red[t + st]); __syncthreads(); }
    float m = red[0];
    __syncthreads();
    float e = (t < NF) ? __expf(s - m) : 0.f;
    ws[t] = e;
    red[t] = e;
    __syncthreads();
    for (int st = 128; st > 0; st >>= 1) { if (t < st) red[t] += red[t + st]; __syncthreads(); }
    float inv = 1.f / red[0];
    const int f0 = g * NF + chunk * 16;
    const unsigned int* q = (const unsigned int*)X + (size_t)f0 * 512 + 256 + t;
    float s0 = 0.f, s1 = 0.f;
    #pragma unroll 4
    for (int f = 0; f < 16; ++f) {
        float a = ws[chunk * 16 + f];
        unsigned u = q[(size_t)f * 512];
        s0 += a * bf2f((unsigned short)(u & 0xffff));
        s1 += a * bf2f((unsigned short)(u >> 16));
    }
    atomicAdd(&outp[g * 512 + 2 * t],     s0 * inv);
    atomicAdd(&outp[g * 512 + 2 * t + 1], s1 * inv);
}

// ---------------------------------------------------------------- batched GEMV body
__device__ __forceinline__ void gemv_body(
    const float* __restrict__ X, int ldx, int dorelu,
    const float* __restrict__ W, int ldw, float* __restrict__ Y, int ldy,
    int nc, int kc, int bc)
{
    __shared__ float xs[4096];
    const int t = threadIdx.x;
    #pragma unroll
    for (int j = 0; j < 16; ++j) {
        int idx = t + j * 256;
        float v = X[(size_t)(bc * 32 + (idx >> 7)) * ldx + kc * 128 + (idx & 127)];
        xs[idx] = dorelu ? (v > 0.f ? v : 0.f) : v;
    }
    __syncthreads();
    const int r = t & 63, bg = t >> 6;
    const int row = nc * 64 + r;
    const float* wrow = W + (size_t)row * ldw + kc * 128;
    float acc[8] = {};
    #pragma unroll 8
    for (int k4 = 0; k4 < 32; ++k4) {
        f32x4 wvv = *(const f32x4*)(wrow + k4 * 4);
        #pragma unroll
        for (int bb = 0; bb < 8; ++bb) {
            f32x4 xv = *(const f32x4*)(xs + (bg * 8 + bb) * 128 + k4 * 4);
            acc[bb] += wvv[0] * xv[0] + wvv[1] * xv[1] + wvv[2] * xv[2] + wvv[3] * xv[3];
        }
    }
    #pragma unroll
    for (int bb = 0; bb < 8; ++bb)
        atomicAdd(&Y[(size_t)(bc * 32 + bg * 8 + bb) * ldy + row], acc[bb]);
}

// update: 3 ops x 8 nc x 4 kc x 2 bc = 192 blocks
__global__ __launch_bounds__(256) void update_kernel(
    const float* __restrict__ Wff_f, const float* __restrict__ Wff_v, const float* __restrict__ Wff_a,
    int iter, const float* __restrict__ fc, const float* __restrict__ vc, const float* __restrict__ a_v,
    float* __restrict__ f_q_p, float* __restrict__ v_q_p, float* __restrict__ a_q_p)
{
    int id = blockIdx.x;
    const int op = id >> 6; id &= 63;
    const int nc = id & 7, kc = (id >> 3) & 3, bc = id >> 5;
    const float* W = (op == 0 ? Wff_f : op == 1 ? Wff_v : Wff_a) + (size_t)iter * 262144;
    const float* X = op == 0 ? fc : op == 1 ? vc : a_v;
    float* Y = op == 0 ? f_q_p : op == 1 ? v_q_p : a_q_p;
    gemv_body(X, 512, 0, W, 512, Y, 512, nc, kc, bc);
}

// generic: grid = NC*KC*2
__global__ __launch_bounds__(256) void gemvb_kernel(
    const float* __restrict__ X, int ldx, int dorelu,
    const float* __restrict__ W, int ldw, float* __restrict__ Y, int ldy,
    int NC, int KC)
{
    int bid = blockIdx.x;
    const int nc = bid % NC; bid /= NC;
    const int kc = bid % KC;
    const int bc = bid / KC;
    gemv_body(X, ldx, dorelu, W, ldw, Y, ldy, nc, kc, bc);
}

// ---------------------------------------------------------------- normalize + build feats
__global__ __launch_bounds__(512) void normfeats_kernel(
    const float* __restrict__ a_q_p, const float* __restrict__ f_q_p, const float* __restrict__ v_q_p,
    const float* __restrict__ metas, float* __restrict__ feats)
{
    __shared__ float red[512];
    const int t = threadIdx.x, b = blockIdx.x;
    float a = a_q_p[b * 512 + t];
    red[t] = a;
    __syncthreads();
    for (int s = 256; s > 0; s >>= 1) { if (t < s) red[t] += red[t + s]; __syncthreads(); }
    float mean = red[0] * (1.f / 512.f);
    __syncthreads();
    float d = a - mean;
    red[t] = d * d;
    __syncthreads();
    for (int s = 256; s > 0; s >>= 1) { if (t < s) red[t] += red[t + s]; __syncthreads(); }
    float sd = sqrtf(red[0] * (1.f / 511.f));
    float* fr = feats + (size_t)b * 1792;
    fr[t]        = f_q_p[b * 512 + t];
    fr[512 + t]  = v_q_p[b * 512 + t];
    fr[1024 + t] = d / sd;
    if (t < 256) {
        float v = 0.f;
        if (t == 0) v = metas[b * 5 + 1] * (1.f / 1500.f);
        else if (t == 1) v = metas[b * 5 + 4] * 0.2f;
        else if (t == 2) {
            float du = metas[b * 5 + 3] - metas[b * 5 + 2];
            v = (du > 8000.f ? 100.f : du) * 0.01f;
        }
        fr[1536 + t] = v;
    }
}

// ---------------------------------------------------------------- MLP layers 3+4
__global__ __launch_bounds__(256) void mlp34_kernel(
    const float* __restrict__ h2acc, const float* __restrict__ W3, const float* __restrict__ W4,
    float* __restrict__ out)
{
    __shared__ float xs[512];
    __shared__ float part[256];
    __shared__ float h3[64];
    const int t = threadIdx.x, b = blockIdx.x;
    {
        float v0 = h2acc[(size_t)b * 512 + t];
        float v1 = h2acc[(size_t)b * 512 + 256 + t];
        xs[t] = v0 > 0.f ? v0 : 0.f;
        xs[256 + t] = v1 > 0.f ? v1 : 0.f;
    }
    __syncthreads();
    const int r = t & 63, q = t >> 6;
    const float* wrow = W3 + (size_t)r * 512 + q * 128;
    float acc = 0.f;
    #pragma unroll 8
    for (int k4 = 0; k4 < 32; ++k4) {
        f32x4 wvv = *(const f32x4*)(wrow + k4 * 4);
        f32x4 xv  = *(const f32x4*)(xs + q * 128 + k4 * 4);
        acc += wvv[0] * xv[0] + wvv[1] * xv[1] + wvv[2] * xv[2] + wvv[3] * xv[3];
    }
    part[t] = acc;
    __syncthreads();
    if (t < 64) {
        float h = part[t] + part[t + 64] + part[t + 128] + part[t + 192];
        h3[t] = h > 0.f ? h : 0.f;
    }
    __syncthreads();
    if (t < 64) {
        float v = h3[t] * W4[t];
        #pragma unroll
        for (int m = 1; m < 64; m <<= 1) v += __shfl_xor(v, m, 64);
        if (t == 0) out[b] = 1.f / (1.f + __expf(-v));
    }
}

// ---------------------------------------------------------------- launch
extern "C" void kernel_launch(void* const* d_in, const int* in_sizes, int n_in,
                              void* d_out, int out_size, void* d_ws, size_t ws_size,
                              hipStream_t stream)
{
    const float* metas  = (const float*)d_in[0];
    const float* frames = (const float*)d_in[2];
    const float* vecs   = (const float*)d_in[4];
    const float* audios = (const float*)d_in[6];
    const float* Wfk   = (const float*)d_in[8];
    const float* Wfv   = (const float*)d_in[9];
    const float* Wvk   = (const float*)d_in[10];
    const float* Wvv   = (const float*)d_in[11];
    const float* Wav   = (const float*)d_in[12];
    const float* Wff_f = (const float*)d_in[13];
    const float* Wff_v = (const float*)d_in[14];
    const float* Wff_a = (const float*)d_in[15];
    const float* Wout1 = (const float*)d_in[16];
    const float* Wout2 = (const float*)d_in[17];
    const float* Wout3 = (const float*)d_in[18];
    const float* Wout4 = (const float*)d_in[19];
    float* out = (float*)d_out;

    char* p = (char*)d_ws;
    auto alloc = [&](size_t n) { char* r = p; p += (n + 255) & ~(size_t)255; return r; };
    unsigned short* fbf = (unsigned short*)alloc(16384ull * 608 * 2);
    unsigned short* wf  = (unsigned short*)alloc(1024ull * 608 * 2);
    unsigned short* vbf = (unsigned short*)alloc(8192ull * 768 * 2);
    unsigned short* wv  = (unsigned short*)alloc(1024ull * 768 * 2);
    unsigned short* Cf  = (unsigned short*)alloc(16384ull * 1024 * 2);
    unsigned short* Cv  = (unsigned short*)alloc(8192ull * 1024 * 2);
    float* W1p   = (float*)alloc(768ull * 1792 * 4);
    float* feats = (float*)alloc(64ull * 1792 * 4);
    // hacc (81920 f) and qbuf (65536 f) contiguous: zeroed as one 147456-float range
    float* hacc  = (float*)alloc(81920ull * 4);            // h1acc (64*768) | h2acc (64*512)
    float* qbuf  = (float*)alloc(2ull * 64 * 512 * 4);     // f_q_p | v_q_p
    float* h1acc = hacc;
    float* h2acc = hacc + 64 * 768;
    float* f_q_p = qbuf;
    float* v_q_p = qbuf + 64 * 512;
    float* a_q_p = (float*)alloc(64ull * 512 * 4);
    float* a_v   = (float*)alloc(64ull * 512 * 4);
    float* fvc   = (float*)alloc(2ull * 64 * 512 * 4);     // fc | vc (zeroed in scores)
    float* fcb   = fvc;
    float* vcb   = fvc + 64 * 512;
    float* sbuf  = (float*)alloc(24576ull * 4);            // f scores | v scores

    prep_kernel<<<2592, 256, 0, stream>>>(frames, Wfk, Wfv, vecs, Wvk, Wvv, Wout1,
                                          audios, Wav, fbf, wf, vbf, wv, W1p, hacc,
                                          a_v, a_q_p);
    gemm_bt_relu<<<1536, 256, 0, stream>>>(fbf, wf, Cf, f_q_p, vbf, wv, Cv, v_q_p);
    for (int i = 0; i < 2; ++i) {
        scores_kernel<<<1536, 256, 0, stream>>>(Cf, Cv, v_q_p, sbuf, fvc);
        pv_kernel<<<1536, 256, 0, stream>>>(Cf, Cv, sbuf, fcb, vcb);
        update_kernel<<<192, 256, 0, stream>>>(Wff_f, Wff_v, Wff_a, i, fcb, vcb, a_v,
                                               f_q_p, v_q_p, a_q_p);
    }
    normfeats_kernel<<<64, 512, 0, stream>>>(a_q_p, f_q_p, v_q_p, metas, feats);
    gemvb_kernel<<<336, 256, 0, stream>>>(feats, 1792, 0, W1p, 1792, h1acc, 768, 12, 14);
    gemvb_kernel<<<96, 256, 0, stream>>>(h1acc, 768, 1, Wout2, 768, h2acc, 512, 8, 6);
    mlp34_kernel<<<64, 256, 0, stream>>>(h2acc, Wout3, Wout4, out);
}